// Round 5
// baseline (186.598 us; speedup 1.0000x reference)
//
#include <hip/hip_runtime.h>
#include <hip/hip_fp16.h>

typedef __attribute__((ext_vector_type(8))) short short8;
typedef __attribute__((ext_vector_type(4))) float f32x4;
typedef unsigned short ushort_t;
typedef unsigned int uint_t;

#define B_SZ 32
#define T_SZ 4096
#define D_IN 256
#define H_SZ 256
#define M_SZ (B_SZ * T_SZ)  // 131072
#define CHUNK 64
#define NCHUNK (T_SZ / CHUNK)   // 64
#define NC_PER_BLK 4
#define GEMM_GRID (M_SZ / (NC_PER_BLK * CHUNK))  // 512

__device__ __forceinline__ ushort_t f2bf(float f) {
  unsigned int u = __float_as_uint(f);
  unsigned int r = (u + 0x7FFFu + ((u >> 16) & 1u)) >> 16;
  return (ushort_t)r;
}

__device__ __forceinline__ float sigmoidf_(float xv) {
  float e = __expf(-fabsf(xv));
  float s = 1.0f / (1.0f + e);
  return xv >= 0.0f ? s : 1.0f - s;
}

__device__ __forceinline__ float unpack_lo(uint_t pk) {
  return __half2float(__ushort_as_half((ushort_t)(pk & 0xFFFFu)));
}
__device__ __forceinline__ float unpack_hi(uint_t pk) {
  return __half2float(__ushort_as_half((ushort_t)(pk >> 16)));
}

// ---------------------------------------------------------------------------
// Kernel 1: pack W'' into bf16 in B-FRAGMENT order (direct-to-register GEMM
// consumption). Granule g = ((grp*8 + ks)*64 + lane), 16 B each:
//   grp = wave_n_group*4 + ct (0..31), ks = kstep (0..7), lane = 0..63.
// Content: W''[n][k0..k0+7] with n = grp*16 + (lane&15),
//   k0 = ks*32 + (lane>>4)*8;  gate = grp&1 (0=Wz,1=Wh), h = (grp>>1)*16+(n&15).
// ---------------------------------------------------------------------------
__global__ void prep_w(const float* __restrict__ Wz, const float* __restrict__ Wh,
                       ushort_t* __restrict__ wsB) {
  int g = blockIdx.x * 256 + threadIdx.x;  // 16384 granules
  if (g >= 32 * 8 * 64) return;
  int lane = g & 63;
  int ks = (g >> 6) & 7;
  int grp = g >> 9;
  int c16 = lane & 15;
  int h = (grp >> 1) * 16 + c16;
  int k0 = ks * 32 + (lane >> 4) * 8;
  const float* W = (grp & 1) ? Wh : Wz;
  const float* src = W + (size_t)h * D_IN + k0;
  ushort_t* dst = wsB + (size_t)g * 8;
#pragma unroll
  for (int j = 0; j < 8; ++j) dst[j] = f2bf(src[j]);
}

// ---------------------------------------------------------------------------
// Kernel 2: GEMM (both gates, N=512 interleaved) + gate math.
// 512 threads = 8 waves; each wave: all 64 rows x its 64-col group (4 ct).
// B: resident in VGPRs (bfr[4][8], 128 regs), loaded once per block.
// A: fp32 DMA'd to LDS via global_load_lds, double-buffered per 64-row
//    chunk; source pre-XOR-swizzled so strided frag reads are conflict-free
//    (rule 21: linear dest + inverse-swizzled source + swizzled read).
// Sync: plain __syncthreads() double-buffer (T3 minimum 2-phase): prefetch
//    chunk cc+1, compute chunk cc, barrier (drains DMA for ALL waves).
// ---------------------------------------------------------------------------
__global__ __launch_bounds__(512, 2) void gemm_av(
    const float* __restrict__ x, const ushort_t* __restrict__ wsB,
    const float* __restrict__ bz, const float* __restrict__ bh,
    uint_t* __restrict__ av) {
  __shared__ __align__(16) float ldsA[2 * CHUNK * D_IN];  // 2 x 64 KB

  const int tid = threadIdx.x;
  const int lane = tid & 63;
  const int wid = tid >> 6;       // 0..7 = N-group
  const int col16 = lane & 15;
  const int rgrp = lane >> 4;     // 0..3
  const size_t rowBase = (size_t)blockIdx.x * (NC_PER_BLK * CHUNK);

  // ---- B fragments: load once, keep in VGPRs ----
  short8 bfr[4][8];
#pragma unroll
  for (int ct = 0; ct < 4; ++ct)
#pragma unroll
    for (int ks = 0; ks < 8; ++ks)
      bfr[ct][ks] =
          *(const short8*)(wsB + ((size_t)(((wid * 4 + ct) * 8 + ks) * 64 + lane)) * 8);

  float bzv[2], bhv[2];
#pragma unroll
  for (int i = 0; i < 2; ++i) {
    int hh = (wid * 2 + i) * 16 + col16;
    bzv[i] = bz[hh];
    bhv[i] = bh[hh];
  }

  // DMA one 64-row fp32 chunk (64 KB) into buffer (cc&1). Wave w stages rows
  // q*8+w. LDS[r][p] = x[r][p ^ ((r&7)<<4)]  (r&7 == wid for staged rows).
  auto STAGE = [&](int cc) {
    const char* xbase = (const char*)(x + (rowBase + (size_t)cc * CHUNK) * D_IN);
    const int soff = (lane * 16) ^ (wid << 4);
    char* lbase = (char*)&ldsA[(cc & 1) * (CHUNK * D_IN)];
#pragma unroll
    for (int q = 0; q < 8; ++q) {
      const int r = q * 8 + wid;
      __builtin_amdgcn_global_load_lds(
          (const __attribute__((address_space(1))) void*)(xbase + (size_t)r * 1024 + soff),
          (__attribute__((address_space(3))) void*)(lbase + r * 1024), 16, 0, 0);
    }
  };

  STAGE(0);
  __syncthreads();  // buf0 ready for all waves

  // swizzled k-offset (bytes) for this lane's A-fragment reads
  const int koffsw = (rgrp * 32) ^ ((lane & 7) << 4);

#pragma unroll 1
  for (int cc = 0; cc < NC_PER_BLK; ++cc) {
    if (cc + 1 < NC_PER_BLK) STAGE(cc + 1);  // prefetch next chunk, other buf

    const char* Ab = (const char*)&ldsA[(cc & 1) * (CHUNK * D_IN)];

    f32x4 acc[4][4];
#pragma unroll
    for (int rt = 0; rt < 4; ++rt)
#pragma unroll
      for (int ct = 0; ct < 4; ++ct) {
        f32x4 z4 = {0.f, 0.f, 0.f, 0.f};
        acc[rt][ct] = z4;
      }

#pragma unroll
    for (int ks = 0; ks < 8; ++ks) {
#pragma unroll
      for (int rt = 0; rt < 4; ++rt) {
        const int row = rt * 16 + col16;      // row&7 == lane&7
        const int a1 = row * 1024 + ks * 128 + koffsw;
        float4 f0 = *(const float4*)(Ab + a1);         // k-floats +0..3
        float4 f1 = *(const float4*)(Ab + (a1 ^ 16));  // k-floats +4..7
        union { ushort_t e[8]; short8 s; } cv;
        cv.e[0] = f2bf(f0.x); cv.e[1] = f2bf(f0.y);
        cv.e[2] = f2bf(f0.z); cv.e[3] = f2bf(f0.w);
        cv.e[4] = f2bf(f1.x); cv.e[5] = f2bf(f1.y);
        cv.e[6] = f2bf(f1.z); cv.e[7] = f2bf(f1.w);
        short8 afr = cv.s;
#pragma unroll
        for (int ct = 0; ct < 4; ++ct)
          acc[rt][ct] = __builtin_amdgcn_mfma_f32_16x16x32_bf16(
              afr, bfr[ct][ks], acc[rt][ct], 0, 0, 0);
      }
    }

    // ---- epilogue: gate math + packed half2(a,v) store ----
    const size_t crow0 = rowBase + (size_t)cc * CHUNK;
#pragma unroll
    for (int i = 0; i < 2; ++i) {
      const int hh = (wid * 2 + i) * 16 + col16;
#pragma unroll
      for (int rt = 0; rt < 4; ++rt) {
#pragma unroll
        for (int j = 0; j < 4; ++j) {
          float kv = acc[rt][2 * i][j] + bzv[i];
          float pv = acc[rt][2 * i + 1][j] + bhv[i];
          float a = sigmoidf_(-kv);   // 1 - sigmoid(k)
          float z = 1.0f - a;         // sigmoid(k)
          float gg = (pv >= 0.0f) ? (pv + 0.5f) : sigmoidf_(pv);
          float vv = z * gg;
          int row = rt * 16 + rgrp * 4 + j;
          uint_t pk = (uint_t)__half_as_ushort(__float2half_rn(a)) |
                      ((uint_t)__half_as_ushort(__float2half_rn(vv)) << 16);
          av[(crow0 + row) * H_SZ + hh] = pk;
        }
      }
    }

    // Drains this iteration's prefetch DMA (vmcnt0+barrier for every wave)
    // AND guarantees all waves finished reading buf(cc&1) before the next
    // iteration's STAGE overwrites it.
    __syncthreads();
  }
}

// ---------------------------------------------------------------------------
// Two-level scan (proven in rounds 2-3): affine composition per CHUNK.
// Phase 1: per (b, chunk): compose 64 steps -> (A, V). 2048 blocks x 256 thr.
// ---------------------------------------------------------------------------
__global__ __launch_bounds__(256) void chunk_reduce(
    const uint_t* __restrict__ av, float2* __restrict__ cAV) {
  const int b = blockIdx.x >> 6;
  const int c = blockIdx.x & 63;
  const int h = threadIdx.x;
  const uint_t* p = av + ((size_t)b * T_SZ + c * CHUNK) * H_SZ + h;

  uint_t buf[CHUNK];
#pragma unroll
  for (int s = 0; s < CHUNK; ++s) buf[s] = p[(size_t)s * H_SZ];

  float A = 1.0f, V = 0.0f;
#pragma unroll
  for (int s = 0; s < CHUNK; ++s) {
    float a = unpack_lo(buf[s]);
    float v = unpack_hi(buf[s]);
    A = a * A;
    V = fmaf(a, V, v);
  }
  float2 r; r.x = A; r.y = V;
  cAV[((size_t)b * NCHUNK + c) * H_SZ + h] = r;
}

// ---------------------------------------------------------------------------
// Phase 2: per (b,h): sequentially compose chunk summaries from g(h0),
// writing the INCOMING h for each chunk. 32 blocks x 256 thr.
// ---------------------------------------------------------------------------
__global__ __launch_bounds__(256) void chunk_carry(
    const float* __restrict__ h0, const float2* __restrict__ cAV,
    float* __restrict__ hb) {
  const int b = blockIdx.x;
  const int h = threadIdx.x;
  float v0 = h0[b * H_SZ + h];
  float hc = (v0 >= 0.0f) ? (v0 + 0.5f) : sigmoidf_(v0);

  const float2* p = cAV + (size_t)b * NCHUNK * H_SZ + h;
  float* o = hb + (size_t)b * NCHUNK * H_SZ + h;

  float2 buf[NCHUNK];
#pragma unroll
  for (int c = 0; c < NCHUNK; ++c) buf[c] = p[(size_t)c * H_SZ];

#pragma unroll
  for (int c = 0; c < NCHUNK; ++c) {
    o[(size_t)c * H_SZ] = hc;
    hc = fmaf(buf[c].x, hc, buf[c].y);
  }
}

// ---------------------------------------------------------------------------
// Phase 3: per (b, chunk): start from carry, re-scan av, write fp32 out.
// av may alias out (in-place fallback): per-thread loads strictly precede
// stores to the same addresses; no __restrict__ on av/out.
// ---------------------------------------------------------------------------
__global__ __launch_bounds__(256) void chunk_scan_out(
    const uint_t* av, const float* __restrict__ hb, float* out) {
  const int b = blockIdx.x >> 6;
  const int c = blockIdx.x & 63;
  const int h = threadIdx.x;

  float hc = hb[((size_t)b * NCHUNK + c) * H_SZ + h];
  const uint_t* p = av + ((size_t)b * T_SZ + c * CHUNK) * H_SZ + h;
  float* o = out + ((size_t)b * T_SZ + c * CHUNK) * H_SZ + h;

  uint_t buf[CHUNK];
#pragma unroll
  for (int s = 0; s < CHUNK; ++s) buf[s] = p[(size_t)s * H_SZ];

#pragma unroll
  for (int s = 0; s < CHUNK; ++s) {
    float a = unpack_lo(buf[s]);
    float v = unpack_hi(buf[s]);
    hc = fmaf(a, hc, v);
    o[(size_t)s * H_SZ] = hc;
  }
}

// Fallback: fully-sequential scan (only if ws too small for summaries).
__global__ __launch_bounds__(64) void scan_seq(const float* __restrict__ h0,
                                               const uint_t* av, float* out) {
  const int b = blockIdx.x >> 2;
  const int hg = blockIdx.x & 3;
  const int h = hg * 64 + threadIdx.x;

  float v0 = h0[b * H_SZ + h];
  float hc = (v0 >= 0.0f) ? (v0 + 0.5f) : sigmoidf_(v0);

  const uint_t* p = av + (size_t)b * T_SZ * H_SZ + h;
  float* o = out + (size_t)b * T_SZ * H_SZ + h;

  uint_t buf[32];
#pragma unroll
  for (int d = 0; d < 32; ++d) buf[d] = p[(size_t)d * H_SZ];

  for (int t0 = 0; t0 < T_SZ; t0 += 32) {
#pragma unroll
    for (int d = 0; d < 32; ++d) {
      int t = t0 + d;
      uint_t pk = buf[d];
      int tn = t + 32;
      if (tn < T_SZ) buf[d] = p[(size_t)tn * H_SZ];
      hc = fmaf(unpack_lo(pk), hc, unpack_hi(pk));
      o[(size_t)t * H_SZ] = hc;
    }
  }
}

extern "C" void kernel_launch(void* const* d_in, const int* in_sizes, int n_in,
                              void* d_out, int out_size, void* d_ws, size_t ws_size,
                              hipStream_t stream) {
  const float* x  = (const float*)d_in[0];
  const float* h0 = (const float*)d_in[1];
  const float* Wz = (const float*)d_in[2];
  const float* bz = (const float*)d_in[3];
  const float* Wh = (const float*)d_in[4];
  const float* bh = (const float*)d_in[5];
  float* out = (float*)d_out;

  // ws layout: [wsB 256K][cAV 4M][hb 2M][pad to 8M][av 134M if it fits]
  const size_t wsBBytes = 262144;
  const size_t cavBytes = (size_t)B_SZ * NCHUNK * H_SZ * 8;   // 4 MiB
  const size_t hbBytes  = (size_t)B_SZ * NCHUNK * H_SZ * 4;   // 2 MiB
  const size_t avOff    = 8388608;
  const size_t avBytes  = (size_t)M_SZ * H_SZ * 4;            // 134 MiB

  ushort_t* wsB = (ushort_t*)d_ws;
  float2* cAV = (float2*)((char*)d_ws + wsBBytes);
  float* hb   = (float*)((char*)d_ws + wsBBytes + cavBytes);

  const bool haveSummaries = ws_size >= wsBBytes + cavBytes + hbBytes;
  uint_t* av;
  if (ws_size >= avOff + avBytes) {
    av = (uint_t*)((char*)d_ws + avOff);
  } else {
    av = (uint_t*)d_out;  // in-place: scan reads av[t] before writing h[t]
  }

  prep_w<<<64, 256, 0, stream>>>(Wz, Wh, wsB);
  gemm_av<<<GEMM_GRID, 512, 0, stream>>>(x, wsB, bz, bh, av);
  if (haveSummaries) {
    chunk_reduce<<<B_SZ * NCHUNK, 256, 0, stream>>>(av, cAV);
    chunk_carry<<<B_SZ, 256, 0, stream>>>(h0, cAV, hb);
    chunk_scan_out<<<B_SZ * NCHUNK, 256, 0, stream>>>(av, hb, out);
  } else {
    scan_seq<<<B_SZ * 4, 64, 0, stream>>>(h0, av, out);
  }
}